// Round 2
// baseline (468.167 us; speedup 1.0000x reference)
//
#include <hip/hip_runtime.h>
#include <hip/hip_bf16.h>
#include <hip/hip_fp8.h>
#include <stdint.h>

#define NN 16384
#define DD 512
#define MARGINV 2.0f
#define EPSV 1e-6f

#define BJ 32
#define JGROUPS 8               // grid = 64 bi x 8 bj = 512 = exactly 2 blocks/CU, zero tail
#define JRANGE (NN / JGROUPS)   // 2048
#define NTILES (JRANGE / BJ)    // 64
#define ROWQ 512                // fp8 row bytes
#define TILEB (BJ * ROWQ)       // 16384 B per tile buffer
#define SQOFF (2 * TILEB)       // sqb LDS offset (8 KB region)

#define KEYMASK  0xFFFFC000     // keep sign+exp+9 mantissa bits; low 14 = j (j<16384)
#define KEYINITF __builtin_bit_cast(float, 0x7F000000)   // big positive finite float
#define PSINIT   __builtin_bit_cast(float, 0x7F7C0000)   // sentinel sqj for first deferred epi
#define BIASV 640.0f            // > max sq_i: keys strictly positive, self provably rank 0

typedef __attribute__((ext_vector_type(4))) float f32x4;
typedef __attribute__((ext_vector_type(4))) int   i32x4;
typedef __attribute__((ext_vector_type(8))) int   i32x8;

#define UNIT_SCALE 0x7F   // E8M0 biased exponent 127 -> x1.0

// ---------------- Kernel 1: row sq-norms (fp32, +BIASV) + fp8 e4m3 quantize ----------------
extern "C" __global__ __launch_bounds__(256)
void prep_kernel(const float* __restrict__ x, unsigned char* __restrict__ xq,
                 float* __restrict__ sqb, float* __restrict__ out) {
  if (blockIdx.x == 0 && threadIdx.x == 0) out[0] = 0.0f;   // replaces memset dispatch
  int row  = blockIdx.x * 4 + (threadIdx.x >> 6);
  int lane = threadIdx.x & 63;
  const float* xr = x + (size_t)row * DD + lane * 8;
  f32x4 a = *(const f32x4*)xr;
  f32x4 b = *(const f32x4*)(xr + 4);
  float s = a[0]*a[0]+a[1]*a[1]+a[2]*a[2]+a[3]*a[3]
          + b[0]*b[0]+b[1]*b[1]+b[2]*b[2]+b[3]*b[3];
  #pragma unroll
  for (int off = 1; off < 64; off <<= 1) s += __shfl_xor(s, off, 64);
  // hardware packed fp8 convert (RNE, same bits as __hip_fp8_e4m3 ctor, no sw path)
  unsigned int w0 = (unsigned int)__builtin_amdgcn_cvt_pk_fp8_f32(a[0], a[1], 0, false);
  w0 = (unsigned int)__builtin_amdgcn_cvt_pk_fp8_f32(a[2], a[3], (int)w0, true);
  unsigned int w1 = (unsigned int)__builtin_amdgcn_cvt_pk_fp8_f32(b[0], b[1], 0, false);
  w1 = (unsigned int)__builtin_amdgcn_cvt_pk_fp8_f32(b[2], b[3], (int)w1, true);
  unsigned long long pk8 = ((unsigned long long)w1 << 32) | (unsigned long long)w0;
  *(unsigned long long*)(xq + (size_t)row * ROWQ + lane * 8) = pk8;
  // key value = sq[j] - 2*dot + BIASV: strictly positive, self (BIASV - sq_i) rank 0
  if (lane == 0) sqb[row] = s + BIASV;
}

// ---------------- Kernel 2: fused MX-fp8 GEMM (X·X^T) + per-row packed top-2 -------------
// Restructure vs r1: (a) top-2-EXCLUDING-SELF instead of top-3 (self provably rank 0;
// merged m1 == global rank 2 == idx3[:,2]); self excluded via compare only on diagonal
// tiles (wave-uniform branch, 1/8 of blocks x 8/64 tiles). (b) DEFERRED EPILOGUE:
// ping-pong accA/accB; each jh's key-pack+insert runs in the middle of the NEXT jh's
// MFMA clusters -> no MFMA-completion wait, VALU hides under MFMA pipe occupancy.
// (c) B-fragment 2-ahead rotation: c+2 loads issued behind cluster c's MFMAs -> only
// c0's lgkm wait exposed per jh. (d) s_setprio(1) around MFMA clusters (T5; the
// deferral creates the wave role-split T5 needs). Register-neutral: +16 acc, -16 m2.
extern "C" __global__ __launch_bounds__(256, 2)
void knn_kernel(const unsigned char* __restrict__ xq, const float* __restrict__ sqb,
                int* __restrict__ pk) {
  __shared__ __align__(16) char lds[2 * TILEB + 8192];  // 40,960 B
  const int tid  = threadIdx.x;
  const int wave = tid >> 6;
  const int lane = tid & 63;
  const int quad = lane >> 4;
  const int r16  = lane & 15;
  const int bi   = blockIdx.x >> 3;             // 0..63
  const int bj   = blockIdx.x & 7;              // 0..7
  const int ibase = bi * 256 + wave * 64;       // 64 i-rows per wave
  const int jbase = bj * JRANGE;

  // stage sqb[jbase .. jbase+2048) into LDS (8 KB)
  #pragma unroll
  for (int p = 0; p < 2; ++p) {
    const float* gs = sqb + jbase + p * 1024 + wave * 256 + lane * 4;
    char* ld = lds + SQOFF + p * 4096 + wave * 1024;
    __builtin_amdgcn_global_load_lds((const __attribute__((address_space(1))) void*)gs,
                                     (__attribute__((address_space(3))) void*)ld,
                                     16, 0, 0);
  }

  // A fragments: 4 sets x 4 k-chunks x 32 B (v8i32). A[m=r16][k=chunk*128+quad*32+t]
  i32x8 afr[4][4];
  #pragma unroll
  for (int s = 0; s < 4; ++s) {
    const unsigned char* ar = xq + (size_t)(ibase + s * 16 + r16) * ROWQ + quad * 32;
    #pragma unroll
    for (int c = 0; c < 4; ++c)
      afr[s][c] = *(const i32x8*)(ar + c * 128);
  }

  // packed top-2 (non-self) per (set s, reg r): q = s*4 + r
  float m0[16], m1[16];
  #pragma unroll
  for (int q = 0; q < 16; ++q) { m0[q] = m1[q] = KEYINITF; }

  auto stage = [&](int jt, int buf) {
    const int jrow0 = jbase + jt * BJ;
    #pragma unroll
    for (int p = 0; p < 4; ++p) {
      const int rr = wave * 8 + p * 2;                     // wave-uniform local row pair
      const int lr = rr + (lane >> 5);                     // per-lane local row
      const int u  = (lane & 31) ^ (lr & 7);               // FULL 3-bit swizzle
      const unsigned char* gsrc = xq + (size_t)(jrow0 + lr) * ROWQ + u * 16;
      char* ldst = lds + buf * TILEB + rr * ROWQ;          // wave-uniform base
      __builtin_amdgcn_global_load_lds((const __attribute__((address_space(1))) void*)gsrc,
                                       (__attribute__((address_space(3))) void*)ldst,
                                       16, 0, 0);
    }
  };

  const int sw = r16 & 7;

  // deferred-epilogue state
  f32x4 accA[4], accB[4];
  #pragma unroll
  for (int s = 0; s < 4; ++s) { accA[s] = f32x4{0.f,0.f,0.f,0.f}; accB[s] = f32x4{0.f,0.f,0.f,0.f}; }
  float psqj  = PSINIT;   // sentinel: first (fake) epilogue inserts keys > KEYINITF
  int   pj    = 0;
  bool  pdiag = false;

#define EPI(A) do {                                                              \
    if (pdiag) {                                                                 \
      _Pragma("unroll") for (int s_ = 0; s_ < 4; ++s_)                           \
      _Pragma("unroll") for (int r_ = 0; r_ < 4; ++r_) {                         \
        float v_ = fmaf(-2.0f, A[s_][r_], psqj);                                 \
        int   b_ = (__builtin_bit_cast(int, v_) & KEYMASK) | pj;                 \
        float u_ = __builtin_bit_cast(float, b_);                                \
        u_ = (pj == (ibase + s_ * 16 + quad * 4 + r_)) ? KEYINITF : u_;          \
        m1[s_*4+r_] = __builtin_amdgcn_fmed3f(m0[s_*4+r_], m1[s_*4+r_], u_);     \
        m0[s_*4+r_] = fminf(m0[s_*4+r_], u_);                                    \
      }                                                                          \
    } else {                                                                     \
      _Pragma("unroll") for (int s_ = 0; s_ < 4; ++s_)                           \
      _Pragma("unroll") for (int r_ = 0; r_ < 4; ++r_) {                         \
        float v_ = fmaf(-2.0f, A[s_][r_], psqj);                                 \
        int   b_ = (__builtin_bit_cast(int, v_) & KEYMASK) | pj;                 \
        float u_ = __builtin_bit_cast(float, b_);                                \
        m1[s_*4+r_] = __builtin_amdgcn_fmed3f(m0[s_*4+r_], m1[s_*4+r_], u_);     \
        m0[s_*4+r_] = fminf(m0[s_*4+r_], u_);                                    \
      }                                                                          \
    }                                                                            \
  } while (0)

#define LDC(BLO, BHI, CC) do {                                                   \
    const int g0_ = (CC) * 8 + quad * 2;                                         \
    BLO = *(const i32x4*)(brow + ((g0_ ^ sw) * 16));                             \
    BHI = *(const i32x4*)(brow + (((g0_ + 1) ^ sw) * 16));                       \
  } while (0)

#define MF4(BLO, BHI, CC, ACC) do {                                              \
    i32x8 bf_ = i32x8{BLO[0],BLO[1],BLO[2],BLO[3],BHI[0],BHI[1],BHI[2],BHI[3]};  \
    __builtin_amdgcn_s_setprio(1);                                               \
    _Pragma("unroll") for (int s_ = 0; s_ < 4; ++s_)                             \
      ACC[s_] = __builtin_amdgcn_mfma_scale_f32_16x16x128_f8f6f4(                \
                  afr[s_][(CC)], bf_, ACC[s_], 0, 0, 0, UNIT_SCALE, 0, UNIT_SCALE); \
    __builtin_amdgcn_s_setprio(0);                                               \
  } while (0)

#define JHBODY(JT, JH, ACCW, ACCR, DIAGT) do {                                   \
    const char* brow = lds + ((JT) & 1) * TILEB + ((JH) * 16 + r16) * ROWQ;      \
    const float sqj_ = *(const float*)(lds + SQOFF + (((JT) * BJ + (JH) * 16 + r16) << 2)); \
    const int j_ = jbase + (JT) * BJ + (JH) * 16 + r16;                          \
    i32x4 b0lo, b0hi, b1lo, b1hi;                                                \
    LDC(b0lo, b0hi, 0);                                                          \
    LDC(b1lo, b1hi, 1);                                                          \
    _Pragma("unroll") for (int s_ = 0; s_ < 4; ++s_) ACCW[s_] = f32x4{0.f,0.f,0.f,0.f}; \
    MF4(b0lo, b0hi, 0, ACCW);                                                    \
    LDC(b0lo, b0hi, 2);                                                          \
    MF4(b1lo, b1hi, 1, ACCW);                                                    \
    LDC(b1lo, b1hi, 3);                                                          \
    EPI(ACCR);              /* deferred epilogue: prev jh's acc, hidden here */  \
    MF4(b0lo, b0hi, 2, ACCW);                                                    \
    MF4(b1lo, b1hi, 3, ACCW);                                                    \
    psqj = sqj_; pj = j_; pdiag = (DIAGT);                                       \
  } while (0)

  stage(0, 0);
  for (int jt = 0; jt < NTILES; ++jt) {
    __syncthreads();
    if (jt + 1 < NTILES) stage(jt + 1, (jt + 1) & 1);
    const bool diagt = ((bi >> 3) == bj) && ((jt >> 3) == (bi & 7));
    JHBODY(jt, 0, accA, accB, diagt);
    JHBODY(jt, 1, accB, accA, diagt);
  }
  EPI(accB);   // drain: last jh's deferred epilogue

  // ------- in-register butterfly merge across r16 (masks 1,2,4,8 stay in-quad) -------
  #pragma unroll
  for (int m = 1; m <= 8; m <<= 1) {
    #pragma unroll
    for (int q = 0; q < 16; ++q) {
      float o0 = __shfl_xor(m0[q], m, 64);
      float o1 = __shfl_xor(m1[q], m, 64);
      m1[q] = __builtin_amdgcn_fmed3f(m0[q], m1[q], o0);
      m0[q] = fminf(m0[q], o0);
      m1[q] = __builtin_amdgcn_fmed3f(m0[q], m1[q], o1);
      m0[q] = fminf(m0[q], o1);
    }
  }

  // lane with r16 == q writes row q's merged packed top-2 (16 writers x 4 quads)
  #pragma unroll
  for (int q = 0; q < 16; ++q) {
    if (r16 == q) {
      int s  = q >> 2, r = q & 3;
      int gi = ibase + s * 16 + quad * 4 + r;
      int ob = (gi * JGROUPS + bj) * 2;
      pk[ob + 0] = __builtin_bit_cast(int, m0[q]);
      pk[ob + 1] = __builtin_bit_cast(int, m1[q]);
    }
  }
#undef EPI
#undef LDC
#undef MF4
#undef JHBODY
}

// ---------------- Kernel 3: merge partials, fp32 norms, hinge, mean ----------------
// 512 blocks x 8 reps; one device atomic per block. Partials are top-2-nonself pairs:
// merged m1 == global rank-2 == idx3[:,2] (self is provably rank 0 by BIASV).
extern "C" __global__ __launch_bounds__(256)
void finalize_kernel(const float* __restrict__ x, const float* __restrict__ pos,
                     const int* __restrict__ pk, float* __restrict__ out) {
  __shared__ float wsum[4];
  int wave = threadIdx.x >> 6;
  int lane = threadIdx.x & 63;
  float acc = 0.f;
  #pragma unroll
  for (int rep = 0; rep < 8; ++rep) {
    int i = rep * 2048 + blockIdx.x * 4 + wave;
    int neg = 0;
    if (lane == 0) {
      float m0 = KEYINITF, m1 = KEYINITF;
      #pragma unroll
      for (int s = 0; s < JGROUPS * 2; ++s) {
        float u = __builtin_bit_cast(float, pk[i * (JGROUPS * 2) + s]);
        m1 = __builtin_amdgcn_fmed3f(m0, m1, u);
        m0 = fminf(m0, u);
      }
      neg = __builtin_bit_cast(int, m1) & 0x3FFF;  // rank 2 overall == idx3[:,2]
    }
    neg = __shfl(neg, 0, 64);
    const float* xr = x   + (size_t)i * DD + lane * 8;
    const float* pr = pos + (size_t)i * DD + lane * 8;
    const float* nr = x   + (size_t)neg * DD + lane * 8;
    f32x4 xa = *(const f32x4*)xr, xb4 = *(const f32x4*)(xr + 4);
    f32x4 pa = *(const f32x4*)pr, pb  = *(const f32x4*)(pr + 4);
    f32x4 na = *(const f32x4*)nr, nb  = *(const f32x4*)(nr + 4);
    float sap = 0.f, san = 0.f;
    #pragma unroll
    for (int k = 0; k < 4; ++k) {
      float d0 = xa[k]  - pa[k] + EPSV; sap = fmaf(d0, d0, sap);
      float d1 = xa[k]  - na[k] + EPSV; san = fmaf(d1, d1, san);
      float d2 = xb4[k] - pb[k] + EPSV; sap = fmaf(d2, d2, sap);
      float d3 = xb4[k] - nb[k] + EPSV; san = fmaf(d3, d3, san);
    }
    #pragma unroll
    for (int off = 1; off < 64; off <<= 1) {
      sap += __shfl_xor(sap, off, 64);
      san += __shfl_xor(san, off, 64);
    }
    if (lane == 0) {
      float l = sqrtf(sap) - sqrtf(san) + MARGINV;
      acc += (l > 0.f ? l : 0.f);
    }
  }
  if (lane == 0) wsum[wave] = acc;
  __syncthreads();
  if (threadIdx.x == 0) {
    atomicAdd(out, (wsum[0] + wsum[1] + wsum[2] + wsum[3]) * (1.0f / NN));
  }
}

// ---------------- host ----------------
extern "C" void kernel_launch(void* const* d_in, const int* in_sizes, int n_in,
                              void* d_out, int out_size, void* d_ws, size_t ws_size,
                              hipStream_t stream) {
  const float* x   = (const float*)d_in[0];
  const float* pos = (const float*)d_in[1];
  char* ws = (char*)d_ws;
  unsigned char* xq  = (unsigned char*)ws;                                // 8 MB
  float* sqb = (float*)(ws + (size_t)NN * ROWQ);                          // 64 KB
  int*   pk  = (int*)  (ws + (size_t)NN * ROWQ + (size_t)NN * 4);         // 1 MB

  prep_kernel<<<NN / 4, 256, 0, stream>>>(x, xq, sqb, (float*)d_out);
  knn_kernel<<<(NN / 256) * JGROUPS, 256, 0, stream>>>(xq, sqb, pk);
  finalize_kernel<<<512, 256, 0, stream>>>(x, pos, pk, (float*)d_out);
}